// Round 21
// baseline (517.449 us; speedup 1.0000x reference)
//
#include <hip/hip_runtime.h>

typedef _Float16 half_t;
typedef _Float16 f16x8 __attribute__((ext_vector_type(8)));
typedef _Float16 f16x4 __attribute__((ext_vector_type(4)));
typedef float    f32x4 __attribute__((ext_vector_type(4)));
typedef float    f32x16 __attribute__((ext_vector_type(16)));

typedef const __attribute__((address_space(1))) void cg_void;
typedef __attribute__((address_space(3))) void lds_void;

#define BB 32
#define LP 2048
#define LQ 512
#define HH 1024

enum { M_QPROJ = 0, M_OUT32 = 1 };

// ---------------- generic f32 -> f16 (count = grid*1024) ----------------
__global__ void cvt16_k(const float* __restrict__ w, half_t* __restrict__ o) {
  long i = ((long)blockIdx.x * 256 + threadIdx.x) * 4;
  f32x4 v = *(const f32x4*)(w + i);
  f16x4 h;
  h[0] = (half_t)v[0]; h[1] = (half_t)v[1]; h[2] = (half_t)v[2]; h[3] = (half_t)v[3];
  *(f16x4*)(o + i) = h;
}

// ------------- fused dual cvt for q_enc AND p_enc in one dispatch -------------
__global__ __launch_bounds__(256) void cvt2_k(const float* __restrict__ qe,
                                              half_t* __restrict__ q16o,
                                              half_t* __restrict__ qT16o,
                                              const float* __restrict__ pe,
                                              half_t* __restrict__ p16o,
                                              half_t* __restrict__ pT16o) {
  __shared__ half_t tile[64 * 64];
  const int byg = blockIdx.y;
  const float* in; half_t* rm; half_t* tr; int R, r0;
  if (byg < 8) { in = qe; rm = q16o; tr = qT16o; R = LQ; r0 = byg * 64; }
  else         { in = pe; rm = p16o; tr = pT16o; R = LP; r0 = (byg - 8) * 64; }
  const int C = HH;
  const long zb = blockIdx.z;
  const float* src = in + zb * (long)R * C;
  half_t* dstT = tr + zb * (long)C * R;
  half_t* dstR = rm + zb * (long)R * C;
  const int c0 = blockIdx.x * 64;
  const int t = threadIdx.x;
  const int cl = (t & 15) * 4;
  const int rl = t >> 4;
#pragma unroll
  for (int rr = 0; rr < 4; rr++) {
    int r = rr * 16 + rl;
    f32x4 v = *(const f32x4*)(src + (long)(r0 + r) * C + c0 + cl);
    f16x4 h;
#pragma unroll
    for (int j = 0; j < 4; j++) {
      h[j] = (half_t)v[j];
      int c = cl + j;
      tile[c * 64 + (r ^ (((c >> 3) & 7) << 3))] = h[j];
    }
    *(f16x4*)(dstR + (long)(r0 + r) * C + c0 + cl) = h;
  }
  __syncthreads();
  const int c = t >> 2;
  const int rch = (t & 3) * 16;
  const int m = (c >> 3) & 7;
  const int B0 = c * 64 + (rch ^ ((m << 3) & 48));
  const int hi = (m & 1) << 3;
  f16x8 g0 = *(const f16x8*)&tile[B0 + hi];
  f16x8 g1 = *(const f16x8*)&tile[B0 + (8 ^ hi)];
  half_t* dp = dstT + (long)(c0 + c) * R + r0 + rch;
  *(f16x8*)dp = g0;
  *(f16x8*)(dp + 8) = g1;
}

// ------------- Pq from E with inline col-stat finalize (stats ONCE per block) -------------
// grid (LQ/64, 1, BB): one block owns a 64-col slab of all LP rows; loops 32 row-tiles.
// Pq[q][p] = E[p][q] * exp(pmg[tile(p)][q] - cmax[q]) * cinv[q]
__global__ __launch_bounds__(256) void pqf_k(const half_t* __restrict__ E,
                                             half_t* __restrict__ out,
                                             const float* __restrict__ pmg,
                                             const float* __restrict__ psg) {
  __shared__ half_t tile[64 * 64];
  const long zb = blockIdx.z;
  const int c0 = blockIdx.x * 64;
  const int t = threadIdx.x;
  const int cl = (t & 15) * 4;
  const int rl = t >> 4;

  // online merge of the 16 per-tile (max,sum) partials for this thread's 4 cols
  const float* mpb = pmg + (long)zb * 16 * LQ + c0 + cl;
  const float* spb = psg + (long)zb * 16 * LQ + c0 + cl;
  float m4[4] = {-3e38f, -3e38f, -3e38f, -3e38f}, s4[4] = {0.f, 0.f, 0.f, 0.f};
#pragma unroll
  for (int tt = 0; tt < 16; ++tt) {
    f32x4 mm = *(const f32x4*)(mpb + (long)tt * LQ);
    f32x4 ss = *(const f32x4*)(spb + (long)tt * LQ);
#pragma unroll
    for (int j = 0; j < 4; ++j) {
      float nm = fmaxf(m4[j], mm[j]);
      s4[j] = s4[j] * __expf(m4[j] - nm) + ss[j] * __expf(mm[j] - nm);
      m4[j] = nm;
    }
  }
  float ci4[4];
#pragma unroll
  for (int j = 0; j < 4; ++j) ci4[j] = 1.f / s4[j];

  const half_t* src = E + zb * (long)LP * LQ;
  half_t* dst = out + zb * (long)LQ * LP;
  const int c = t >> 2;
  const int rch = (t & 3) * 16;
  const int mswz = (c >> 3) & 7;
  const int B0 = c * 64 + (rch ^ ((mswz << 3) & 48));
  const int hi = (mswz & 1) << 3;

  for (int rt = 0; rt < LP / 64; ++rt) {
    const int r0 = rt * 64;
    const int tIdx = r0 >> 7;
    f32x4 tm = *(const f32x4*)(mpb + (long)tIdx * LQ);
    float sc[4];
#pragma unroll
    for (int j = 0; j < 4; ++j) sc[j] = __expf(tm[j] - m4[j]) * ci4[j];
#pragma unroll
    for (int rr = 0; rr < 4; rr++) {
      int r = rr * 16 + rl;
      f16x4 v = *(const f16x4*)(src + (long)(r0 + r) * LQ + c0 + cl);
#pragma unroll
      for (int j = 0; j < 4; j++) {
        float x = (float)v[j] * sc[j];
        int cc = cl + j;
        tile[cc * 64 + (r ^ (((cc >> 3) & 7) << 3))] = (half_t)x;
      }
    }
    __syncthreads();
    f16x8 g0 = *(const f16x8*)&tile[B0 + hi];
    f16x8 g1 = *(const f16x8*)&tile[B0 + (8 ^ hi)];
    half_t* dp = dst + (long)(c0 + c) * LP + r0 + rch;
    *(f16x8*)dp = g0;
    *(f16x8*)(dp + 8) = g1;
    __syncthreads();  // protect tile before next iteration overwrites
  }
}

// ---------------- staging (8 waves): [ROWS][32] f16 via gload_lds; slot XOR (row>>1)&3 ----------------
template<int ROWS>
__device__ __forceinline__ void stage_op(const half_t* src, int ld,
                                         half_t* lds_base, int wid, int lane) {
  const int goff = (((lane & 3) ^ ((lane >> 3) & 3)) << 3);
#pragma unroll
  for (int j = 0; j < ROWS / 128; ++j) {
    int row = j * 128 + wid * 16 + (lane >> 2);
    const half_t* g = src + (long)row * ld + goff;
    __builtin_amdgcn_global_load_lds((cg_void*)g,
        (lds_void*)(lds_base + j * 4096 + wid * 512), 16, 0, 0);
  }
}

__device__ __forceinline__ void xcd_swz(long lid, long nwg, long& out) {
  const long q8 = nwg >> 3, r8 = nwg & 7;
  const long xcd = lid & 7, rest = lid >> 3;
  out = (xcd < r8 ? xcd * (q8 + 1) : r8 * (q8 + 1) + (xcd - r8) * q8) + rest;
}

// ---------------- fused att GEMM (32x32x16) + dual softmax prep (r19 exact) ----------------
__global__ __launch_bounds__(512, 2) void attf_k(
    const half_t* __restrict__ Ap, const half_t* __restrict__ Bp,
    half_t* __restrict__ PpO, half_t* __restrict__ EO,
    float* __restrict__ pmg, float* __restrict__ psg) {
  __shared__ __align__(16) half_t As[3 * 4096];
  __shared__ __align__(16) half_t Bs[3 * 16384];
  __shared__ float rmL[4][128];
  __shared__ float cmL[2][512];
  __shared__ float rsL[4][128];
  __shared__ float csL[2][512];

  const int nby = gridDim.y;  // 16
  long lid;
  xcd_swz(blockIdx.y + (long)nby * blockIdx.z, (long)nby * gridDim.z, lid);
  const int by = (int)(lid % nby);
  const int bz = (int)(lid / nby);

  const int t0 = threadIdx.x;
  const int lane = t0 & 63;
  const int wid = t0 >> 6;
  const int wm = wid >> 2, wn = wid & 3;
  const int m0 = by * 128;

  const half_t* Abase = Ap + ((long)bz * LP + m0) * HH;
  const half_t* Bbase = Bp + (long)bz * LQ * HH;

  const int c5 = lane & 31, hi = lane >> 5;
  const int sx = (c5 >> 1) & 3;
  const int ofs0 = c5 * 32 + ((hi ^ sx) << 3);
  const int ofs1 = c5 * 32 + (((2 | hi) ^ sx) << 3);

  f32x16 acc[2][4] = {};
  const int NT = HH / 32;   // 32

#pragma unroll
  for (int tt = 0; tt < 2; ++tt) {
    stage_op<128>(Abase + tt * 32, HH, As + tt * 4096, wid, lane);
    stage_op<512>(Bbase + tt * 32, HH, Bs + tt * 16384, wid, lane);
  }

  for (int t = 0; t < NT; ++t) {
    if (t + 1 < NT) asm volatile("s_waitcnt vmcnt(5)" ::: "memory");
    else            asm volatile("s_waitcnt vmcnt(0)" ::: "memory");
    __builtin_amdgcn_s_barrier();
    asm volatile("" ::: "memory");

    const half_t* Au = As + (t % 3) * 4096;
    const half_t* Bu = Bs + (t % 3) * 16384;
    f16x8 af[2][2], bf[4][2];
#pragma unroll
    for (int mf = 0; mf < 2; ++mf) {
      const half_t* p = Au + (wm * 64 + mf * 32) * 32;
      af[mf][0] = *(const f16x8*)(p + ofs0);
      af[mf][1] = *(const f16x8*)(p + ofs1);
    }
#pragma unroll
    for (int nf = 0; nf < 4; ++nf) {
      const half_t* p = Bu + (wn * 128 + nf * 32) * 32;
      bf[nf][0] = *(const f16x8*)(p + ofs0);
      bf[nf][1] = *(const f16x8*)(p + ofs1);
    }
    if (t + 2 < NT) {
      const int u2 = (t + 2) % 3;
      stage_op<128>(Abase + (t + 2) * 32, HH, As + u2 * 4096, wid, lane);
      stage_op<512>(Bbase + (t + 2) * 32, HH, Bs + u2 * 16384, wid, lane);
    }
    __builtin_amdgcn_s_setprio(1);
#pragma unroll
    for (int mf = 0; mf < 2; ++mf)
#pragma unroll
      for (int nf = 0; nf < 4; ++nf) {
        acc[mf][nf] = __builtin_amdgcn_mfma_f32_32x32x16_f16(af[mf][0], bf[nf][0], acc[mf][nf], 0, 0, 0);
        acc[mf][nf] = __builtin_amdgcn_mfma_f32_32x32x16_f16(af[mf][1], bf[nf][1], acc[mf][nf], 0, 0, 0);
      }
    __builtin_amdgcn_s_setprio(0);
  }

  // ===== pass1: row max / col max; pmg write =====
  float rmv[2][16], cmv[4];
#pragma unroll
  for (int m = 0; m < 2; ++m)
#pragma unroll
    for (int r = 0; r < 16; ++r) {
      float v = fmaxf(fmaxf(acc[m][0][r], acc[m][1][r]), fmaxf(acc[m][2][r], acc[m][3][r]));
#pragma unroll
      for (int o = 1; o < 32; o <<= 1) v = fmaxf(v, __shfl_xor(v, o, 64));
      rmv[m][r] = v;
    }
#pragma unroll
  for (int n = 0; n < 4; ++n) {
    float v = acc[0][n][0];
#pragma unroll
    for (int m = 0; m < 2; ++m)
#pragma unroll
      for (int r = 0; r < 16; ++r) v = fmaxf(v, acc[m][n][r]);
    v = fmaxf(v, __shfl_xor(v, 32, 64));
    cmv[n] = v;
  }
  if (c5 < 16) {
#pragma unroll
    for (int m = 0; m < 2; ++m)
      rmL[wn][wm * 64 + m * 32 + (c5 & 3) + 8 * (c5 >> 2) + 4 * hi] = rmv[m][c5];
  }
  if (hi == 0) {
#pragma unroll
    for (int n = 0; n < 4; ++n) cmL[wm][wn * 128 + n * 32 + c5] = cmv[n];
  }
  __syncthreads();
  if (t0 < 128)
    rmL[0][t0] = fmaxf(fmaxf(rmL[0][t0], rmL[1][t0]), fmaxf(rmL[2][t0], rmL[3][t0]));
  {
    float cm2 = fmaxf(cmL[0][t0 & 511], cmL[1][t0 & 511]);
    cmL[0][t0 & 511] = cm2;
    pmg[((long)bz * 16 + by) * LQ + (t0 & 511)] = cm2;
  }
  __syncthreads();
#pragma unroll
  for (int m = 0; m < 2; ++m)
#pragma unroll
    for (int r = 0; r < 16; ++r)
      rmv[m][r] = rmL[0][wm * 64 + m * 32 + (r & 3) + 8 * (r >> 2) + 4 * hi];
#pragma unroll
  for (int n = 0; n < 4; ++n) cmv[n] = cmL[0][wn * 128 + n * 32 + c5];

  // ===== pass2 (merged): one exp pass -> E store + col sums + row sums; acc <- p =====
  half_t* EB = EO + (long)bz * LP * LQ;
  float csW[4] = {0.f, 0.f, 0.f, 0.f};
  float rowS[2][16];
#pragma unroll
  for (int m = 0; m < 2; ++m)
#pragma unroll
    for (int r = 0; r < 16; ++r) {
      long grow = (long)(m0 + wm * 64 + m * 32 + (r & 3) + 8 * (r >> 2) + 4 * hi) * LQ;
      float s = 0.f;
#pragma unroll
      for (int n = 0; n < 4; ++n) {
        float a = acc[m][n][r];
        float e = __expf(a - cmv[n]);
        float p = __expf(a - rmv[m][r]);
        csW[n] += e;
        EB[grow + wn * 128 + n * 32 + c5] = (half_t)e;
        acc[m][n][r] = p;
        s += p;
      }
#pragma unroll
      for (int o = 1; o < 32; o <<= 1) s += __shfl_xor(s, o, 64);
      rowS[m][r] = s;
    }
#pragma unroll
  for (int n = 0; n < 4; ++n) csW[n] += __shfl_xor(csW[n], 32, 64);
  if (c5 < 16) {
#pragma unroll
    for (int m = 0; m < 2; ++m)
      rsL[wn][wm * 64 + m * 32 + (c5 & 3) + 8 * (c5 >> 2) + 4 * hi] = rowS[m][c5];
  }
  if (hi == 0) {
#pragma unroll
    for (int n = 0; n < 4; ++n) csL[wm][wn * 128 + n * 32 + c5] = csW[n];
  }
  __syncthreads();
  if (t0 < 128)
    rsL[0][t0] = 1.f / (rsL[0][t0] + rsL[1][t0] + rsL[2][t0] + rsL[3][t0]);
  psg[((long)bz * 16 + by) * LQ + (t0 & 511)] = csL[0][t0 & 511] + csL[1][t0 & 511];
  __syncthreads();

  // ===== pass3: Pp = p * rinv =====
  half_t* PpB = PpO + (long)bz * LP * LQ;
#pragma unroll
  for (int m = 0; m < 2; ++m)
#pragma unroll
    for (int r = 0; r < 16; ++r) {
      int row = wm * 64 + m * 32 + (r & 3) + 8 * (r >> 2) + 4 * hi;
      long grow = (long)(m0 + row) * LQ;
      float ri = rsL[0][row];
#pragma unroll
      for (int n = 0; n < 4; ++n)
        PpB[grow + wn * 128 + n * 32 + c5] = (half_t)(acc[m][n][r] * ri);
    }
}

// ================= 8-phase 256x256 GEMM core (lead-6, graded tail; r19 exact) =================
__device__ __forceinline__ void stage_half(const half_t* src, int ld, int k0,
                                           half_t* slot, int half_id, int wid, int lane) {
#pragma unroll
  for (int j = 0; j < 2; ++j) {
    int c = j * 512 + wid * 64 + lane;
    int lr = c >> 3, sl = c & 7;
    int gr = (lr & 63) + half_id * 64 + (lr >> 6) * 128;
    const half_t* g = src + (long)gr * ld + k0 + (((sl ^ (lr & 7))) << 3);
    __builtin_amdgcn_global_load_lds((cg_void*)g,
        (lds_void*)(slot + j * 4096 + wid * 512), 16, 0, 0);
  }
}

__device__ __forceinline__ void stage_s(int s, const half_t* Ab, const half_t* Bb,
                                        int lda, int ldb, half_t* lds, int NT,
                                        int wid, int lane) {
  int ts = s >> 2;
  if (ts >= NT) return;
  int kind = s & 3;
  half_t* slot = lds + (s & 7) * 8192;
  int k0 = ts * 64;
  if (kind == 0)      stage_half(Ab, lda, k0, slot, 0, wid, lane);
  else if (kind == 1) stage_half(Bb, ldb, k0, slot, 0, wid, lane);
  else if (kind == 2) stage_half(Bb, ldb, k0, slot, 1, wid, lane);
  else                stage_half(Ab, lda, k0, slot, 1, wid, lane);
}

template<int MODE>
__device__ __forceinline__ void core8p(const half_t* __restrict__ Ab,
                                       const half_t* __restrict__ Bb,
                                       void* __restrict__ cB,
                                       const float* __restrict__ biasB,
                                       int lda, int ldb, int ldc, int K,
                                       half_t* lds) {
  const int t0 = threadIdx.x;
  const int lane = t0 & 63;
  const int wid = t0 >> 6;
  const int wm = wid >> 2, wn = wid & 3;   // 2 x 4 waves
  const int fr = lane & 15, fs = lane >> 4;

  f32x4 acc[8][4] = {};
  const int NT = K >> 6;                   // K-tiles of 64

  // prologue: stages s=0..5 (lead 6); vmcnt(6) -> s<=2 resident
#pragma unroll
  for (int s = 0; s < 6; ++s) stage_s(s, Ab, Bb, lda, ldb, lds, NT, wid, lane);
  asm volatile("s_waitcnt vmcnt(6)" ::: "memory");
  __builtin_amdgcn_s_barrier();
  asm volatile("" ::: "memory");

  for (int t = 0; t < NT; ++t) {
    const int base4 = 4 * t;
    const half_t* slotA0 = lds + ((base4) & 7) * 8192;
    const half_t* slotB0 = lds + ((base4 + 1) & 7) * 8192;
    const half_t* slotB1 = lds + ((base4 + 2) & 7) * 8192;
    const half_t* slotA1 = lds + ((base4 + 3) & 7) * 8192;
    f16x8 bf[4][2];
#pragma unroll
    for (int p = 0; p < 4; ++p) {
      // ---- ds reads for this phase (guaranteed by previous phase's wait) ----
      f16x8 af[2][2];
      const half_t* aslot = (p < 2) ? slotA0 : slotA1;
      const int lrbase = wm * 64 + (p & 1) * 32;
#pragma unroll
      for (int i = 0; i < 2; ++i) {
        int lr = lrbase + i * 16 + fr;
#pragma unroll
        for (int kh = 0; kh < 2; ++kh)
          af[i][kh] = *(const f16x8*)&aslot[lr * 64 + (((fs + 4 * kh) ^ (lr & 7)) << 3)];
      }
      if (p == 0) {
        const half_t* bslot = (wn & 1) ? slotB1 : slotB0;
#pragma unroll
        for (int nf = 0; nf < 4; ++nf) {
          int lr = (wn >> 1) * 64 + nf * 16 + fr;
#pragma unroll
          for (int kh = 0; kh < 2; ++kh)
            bf[nf][kh] = *(const f16x8*)&bslot[lr * 64 + (((fs + 4 * kh) ^ (lr & 7)) << 3)];
        }
      }
      // ---- stage one half-tile (stream, lead 6) ----
      stage_s(base4 + p + 6, Ab, Bb, lda, ldb, lds, NT, wid, lane);
      // ---- graded counted wait ----
      if (t + 2 < NT) {
        asm volatile("s_waitcnt vmcnt(6)" ::: "memory");
      } else if (t + 2 == NT) {
        if (p < 2)       asm volatile("s_waitcnt vmcnt(6)" ::: "memory");
        else if (p == 2) asm volatile("s_waitcnt vmcnt(4)" ::: "memory");
        else             asm volatile("s_waitcnt vmcnt(2)" ::: "memory");
      } else {
        asm volatile("s_waitcnt vmcnt(0)" ::: "memory");
      }
      __builtin_amdgcn_s_barrier();
      asm volatile("s_waitcnt lgkmcnt(0)" ::: "memory");
      __builtin_amdgcn_sched_barrier(0);
      __builtin_amdgcn_s_setprio(1);
#pragma unroll
      for (int kh = 0; kh < 2; ++kh)
#pragma unroll
        for (int i = 0; i < 2; ++i)
#pragma unroll
          for (int nf = 0; nf < 4; ++nf)
            acc[p * 2 + i][nf] =
                __builtin_amdgcn_mfma_f32_16x16x32_f16(af[i][kh], bf[nf][kh], acc[p * 2 + i][nf], 0, 0, 0);
      __builtin_amdgcn_s_setprio(0);
      __builtin_amdgcn_s_barrier();
      asm volatile("" ::: "memory");
    }
  }

  // ---- epilogue: D row=(lane>>4)*4+j, col=lane&15 ----
  const int r0 = fs * 4;
#pragma unroll
  for (int nf = 0; nf < 4; ++nf) {
    int col = wn * 64 + nf * 16 + fr;
    float bv = 0.f;
    if constexpr (MODE == M_QPROJ) bv = biasB[col];
#pragma unroll
    for (int mf = 0; mf < 8; ++mf) {
      int row = wm * 128 + (mf >> 2) * 64 + ((mf >> 1) & 1) * 32 + (mf & 1) * 16 + r0;
#pragma unroll
      for (int j = 0; j < 4; j++) {
        if constexpr (MODE == M_QPROJ)
          ((half_t*)cB)[(long)(row + j) * ldc + col] = (half_t)(acc[mf][nf][j] + bv);
        else
          ((float*)cB)[(long)(row + j) * ldc + col] = acc[mf][nf][j];
      }
    }
  }
}

// qproj: grid (4, 64) = 256 blocks
__global__ __launch_bounds__(512, 1) void gemmq_k(const half_t* __restrict__ q16,
                                                  const half_t* __restrict__ w16,
                                                  half_t* __restrict__ qpj,
                                                  const float* __restrict__ Gb) {
  __shared__ __align__(16) half_t lds[8 * 8192];
  long lid;
  xcd_swz(blockIdx.x + 4L * blockIdx.y, 4L * gridDim.y, lid);
  const int bx = (int)(lid % 4);
  const int by = (int)(lid / 4);
  core8p<M_QPROJ>(q16 + (long)(by * 256) * HH,
                  w16 + (long)(bx * 256) * HH,
                  qpj + (long)(by * 256) * HH + bx * 256,
                  Gb + bx * 256, HH, HH, HH, HH, lds);
}

// fused m_p + m_q: grid (4, 10, 32); by<2 -> m_q tile (long K, starts early), else m_p
__global__ __launch_bounds__(512, 1) void gemm2_k(
    const half_t* __restrict__ Pp, const half_t* __restrict__ qT16, float* __restrict__ m_p,
    const half_t* __restrict__ Pq, const half_t* __restrict__ pT16, float* __restrict__ m_q) {
  __shared__ __align__(16) half_t lds[8 * 8192];
  long lid;
  xcd_swz(blockIdx.x + 4L * (blockIdx.y + 10L * blockIdx.z), 4L * 10 * 32, lid);
  const int bx = (int)(lid % 4);
  const long tmp = lid / 4;
  const int by = (int)(tmp % 10);
  const int bz = (int)(tmp / 10);

  if (by < 2) {
    core8p<M_OUT32>(Pq + (long)bz * LQ * LP + (long)(by * 256) * LP,
                    pT16 + (long)bz * HH * LP + (long)(bx * 256) * LP,
                    m_q + (long)bz * LQ * HH + (long)(by * 256) * HH + bx * 256,
                    nullptr, LP, LP, HH, LP, lds);
  } else {
    const int py = by - 2;
    core8p<M_OUT32>(Pp + (long)bz * LP * LQ + (long)(py * 256) * LQ,
                    qT16 + (long)bz * HH * LQ + (long)(bx * 256) * LQ,
                    m_p + (long)bz * LP * HH + (long)(py * 256) * HH + bx * 256,
                    nullptr, LQ, LQ, HH, LQ, lds);
  }
}

extern "C" void kernel_launch(void* const* d_in, const int* in_sizes, int n_in,
                              void* d_out, int out_size, void* d_ws, size_t ws_size,
                              hipStream_t stream) {
  const float* p_enc = (const float*)d_in[0];  // [B, LP, H]
  const float* q_enc = (const float*)d_in[1];  // [B, LQ, H]
  const float* Gw    = (const float*)d_in[2];  // [H, H]
  const float* Gb    = (const float*)d_in[3];  // [H]
  float* m_p = (float*)d_out;
  float* m_q = m_p + (long)BB * LP * HH;

  // workspace carve (~548 MB, ws is ~1.25 GiB)
  half_t* w16   = (half_t*)d_ws;                    // HH*HH
  half_t* q16   = w16 + (long)HH * HH;              // BB*LQ*HH
  half_t* qT16  = q16 + (long)BB * LQ * HH;         // BB*HH*LQ
  half_t* qpj16 = qT16 + (long)BB * HH * LQ;        // BB*LQ*HH
  half_t* p16   = qpj16 + (long)BB * LQ * HH;       // BB*LP*HH
  half_t* pT16  = p16 + (long)BB * LP * HH;         // BB*HH*LP
  half_t* Pp    = pT16 + (long)BB * HH * LP;        // BB*LP*LQ
  half_t* Ebuf  = Pp + (long)BB * LP * LQ;          // BB*LP*LQ
  half_t* Pq    = Ebuf + (long)BB * LP * LQ;        // BB*LQ*LP
  float*  pmg   = (float*)(Pq + (long)BB * LQ * LP);  // BB*16*LQ
  float*  psg   = pmg + (long)BB * 16 * LQ;           // BB*16*LQ

  cvt16_k<<<HH * HH / 1024, 256, 0, stream>>>(Gw, w16);

  // fused q+p cvt/transpose
  cvt2_k<<<dim3(HH / 64, 40, BB), 256, 0, stream>>>(q_enc, q16, qT16, p_enc, p16, pT16);

  // qproj16 = q16 . w16^T + Gb   (M=16384, N=HH, K=HH) — 8-phase core
  gemmq_k<<<dim3(4, 64, 1), 512, 0, stream>>>(q16, w16, qpj16, Gb);

  // fused att GEMM: Pp, E, col partials
  attf_k<<<dim3(1, LP / 128, BB), 512, 0, stream>>>(p16, qpj16, Pp, Ebuf, pmg, psg);

  // Pq from E (col-stat finalize folded, stats once per block)
  pqf_k<<<dim3(LQ / 64, 1, BB), 256, 0, stream>>>(Ebuf, Pq, pmg, psg);

  // fused m_p + m_q (8-phase core, lead-6 / graded-tail counted vmcnt)
  gemm2_k<<<dim3(4, 10, BB), 512, 0, stream>>>(Pp, qT16, m_p, Pq, pT16, m_q);
}

// Round 22
// 497.272 us; speedup vs baseline: 1.0406x; 1.0406x over previous
//
#include <hip/hip_runtime.h>

typedef _Float16 half_t;
typedef _Float16 f16x8 __attribute__((ext_vector_type(8)));
typedef _Float16 f16x4 __attribute__((ext_vector_type(4)));
typedef float    f32x4 __attribute__((ext_vector_type(4)));
typedef float    f32x16 __attribute__((ext_vector_type(16)));

typedef const __attribute__((address_space(1))) void cg_void;
typedef __attribute__((address_space(3))) void lds_void;

#define BB 32
#define LP 2048
#define LQ 512
#define HH 1024

enum { M_QPROJ = 0, M_OUT32 = 1 };

// ---------------- generic f32 -> f16 (count = grid*1024) ----------------
__global__ void cvt16_k(const float* __restrict__ w, half_t* __restrict__ o) {
  long i = ((long)blockIdx.x * 256 + threadIdx.x) * 4;
  f32x4 v = *(const f32x4*)(w + i);
  f16x4 h;
  h[0] = (half_t)v[0]; h[1] = (half_t)v[1]; h[2] = (half_t)v[2]; h[3] = (half_t)v[3];
  *(f16x4*)(o + i) = h;
}

// ------------- fused dual cvt for q_enc AND p_enc in one dispatch -------------
__global__ __launch_bounds__(256) void cvt2_k(const float* __restrict__ qe,
                                              half_t* __restrict__ q16o,
                                              half_t* __restrict__ qT16o,
                                              const float* __restrict__ pe,
                                              half_t* __restrict__ p16o,
                                              half_t* __restrict__ pT16o) {
  __shared__ half_t tile[64 * 64];
  const int byg = blockIdx.y;
  const float* in; half_t* rm; half_t* tr; int R, r0;
  if (byg < 8) { in = qe; rm = q16o; tr = qT16o; R = LQ; r0 = byg * 64; }
  else         { in = pe; rm = p16o; tr = pT16o; R = LP; r0 = (byg - 8) * 64; }
  const int C = HH;
  const long zb = blockIdx.z;
  const float* src = in + zb * (long)R * C;
  half_t* dstT = tr + zb * (long)C * R;
  half_t* dstR = rm + zb * (long)R * C;
  const int c0 = blockIdx.x * 64;
  const int t = threadIdx.x;
  const int cl = (t & 15) * 4;
  const int rl = t >> 4;
#pragma unroll
  for (int rr = 0; rr < 4; rr++) {
    int r = rr * 16 + rl;
    f32x4 v = *(const f32x4*)(src + (long)(r0 + r) * C + c0 + cl);
    f16x4 h;
#pragma unroll
    for (int j = 0; j < 4; j++) {
      h[j] = (half_t)v[j];
      int c = cl + j;
      tile[c * 64 + (r ^ (((c >> 3) & 7) << 3))] = h[j];
    }
    *(f16x4*)(dstR + (long)(r0 + r) * C + c0 + cl) = h;
  }
  __syncthreads();
  const int c = t >> 2;
  const int rch = (t & 3) * 16;
  const int m = (c >> 3) & 7;
  const int B0 = c * 64 + (rch ^ ((m << 3) & 48));
  const int hi = (m & 1) << 3;
  f16x8 g0 = *(const f16x8*)&tile[B0 + hi];
  f16x8 g1 = *(const f16x8*)&tile[B0 + (8 ^ hi)];
  half_t* dp = dstT + (long)(c0 + c) * R + r0 + rch;
  *(f16x8*)dp = g0;
  *(f16x8*)(dp + 8) = g1;
}

// ---------------- finalize col stats from 16 per-m-tile partials ----------------
__global__ __launch_bounds__(256) void cfin_k(const float* __restrict__ pmg,
                                              const float* __restrict__ psg,
                                              float* __restrict__ cmax,
                                              float* __restrict__ cinv) {
  long i = (long)blockIdx.x * 256 + threadIdx.x;  // b*LQ + q
  long b = i / LQ, q = i - b * LQ;
  const float* mp = pmg + (b * 16) * LQ + q;
  const float* sp = psg + (b * 16) * LQ + q;
  float m = -3e38f, s = 0.f;
#pragma unroll
  for (int t = 0; t < 16; t++) {
    float mm = mp[(long)t * LQ], ss = sp[(long)t * LQ];
    float nm = fmaxf(m, mm);
    s = s * __expf(m - nm) + ss * __expf(mm - nm);
    m = nm;
  }
  cmax[i] = m;
  cinv[i] = 1.f / s;
}

// ------------- Pq from E: Pq[q][p] = E[p][q]*exp(pmg[tile][q]-cmax[q])*cinv[q] -------------
__global__ __launch_bounds__(256) void pq_k(const half_t* __restrict__ E,
                                            half_t* __restrict__ out,
                                            const float* __restrict__ pmg,
                                            const float* __restrict__ cmax,
                                            const float* __restrict__ cinv) {
  __shared__ half_t tile[64 * 64];
  const long zb = blockIdx.z;
  const half_t* src = E + zb * (long)LP * LQ;
  half_t* dst = out + zb * (long)LQ * LP;
  const int r0 = blockIdx.y * 64, c0 = blockIdx.x * 64;
  const int tIdx = r0 >> 7;
  const int t = threadIdx.x;
  const int cl = (t & 15) * 4;
  const int rl = t >> 4;
  f32x4 tm = *(const f32x4*)(pmg + ((long)zb * 16 + tIdx) * LQ + c0 + cl);
  f32x4 cm = *(const f32x4*)(cmax + (long)zb * LQ + c0 + cl);
  f32x4 ci = *(const f32x4*)(cinv + (long)zb * LQ + c0 + cl);
  float sc[4];
#pragma unroll
  for (int j = 0; j < 4; j++) sc[j] = __expf(tm[j] - cm[j]) * ci[j];
#pragma unroll
  for (int rr = 0; rr < 4; rr++) {
    int r = rr * 16 + rl;
    f16x4 v = *(const f16x4*)(src + (long)(r0 + r) * LQ + c0 + cl);
#pragma unroll
    for (int j = 0; j < 4; j++) {
      float x = (float)v[j] * sc[j];
      int c = cl + j;
      tile[c * 64 + (r ^ (((c >> 3) & 7) << 3))] = (half_t)x;
    }
  }
  __syncthreads();
  const int c = t >> 2;
  const int rch = (t & 3) * 16;
  const int m = (c >> 3) & 7;
  const int B0 = c * 64 + (rch ^ ((m << 3) & 48));
  const int hi = (m & 1) << 3;
  f16x8 g0 = *(const f16x8*)&tile[B0 + hi];
  f16x8 g1 = *(const f16x8*)&tile[B0 + (8 ^ hi)];
  half_t* dp = dst + (long)(c0 + c) * LP + r0 + rch;
  *(f16x8*)dp = g0;
  *(f16x8*)(dp + 8) = g1;
}

// ---------------- staging (8 waves): [ROWS][32] f16 via gload_lds; slot XOR (row>>1)&3 ----------------
template<int ROWS>
__device__ __forceinline__ void stage_op(const half_t* src, int ld,
                                         half_t* lds_base, int wid, int lane) {
  const int goff = (((lane & 3) ^ ((lane >> 3) & 3)) << 3);
#pragma unroll
  for (int j = 0; j < ROWS / 128; ++j) {
    int row = j * 128 + wid * 16 + (lane >> 2);
    const half_t* g = src + (long)row * ld + goff;
    __builtin_amdgcn_global_load_lds((cg_void*)g,
        (lds_void*)(lds_base + j * 4096 + wid * 512), 16, 0, 0);
  }
}

__device__ __forceinline__ void xcd_swz(long lid, long nwg, long& out) {
  const long q8 = nwg >> 3, r8 = nwg & 7;
  const long xcd = lid & 7, rest = lid >> 3;
  out = (xcd < r8 ? xcd * (q8 + 1) : r8 * (q8 + 1) + (xcd - r8) * q8) + rest;
}

// ---------------- fused att GEMM (32x32x16) + dual softmax prep ----------------
// Per-THREAD loads per K-tile = 5 (A:1 + B:4); vmcnt(5) = maximal legal counted wait:
// drains tile t exactly, keeps tile t+1's 5 loads in flight.
__global__ __launch_bounds__(512, 2) void attf_k(
    const half_t* __restrict__ Ap, const half_t* __restrict__ Bp,
    half_t* __restrict__ PpO, half_t* __restrict__ EO,
    float* __restrict__ pmg, float* __restrict__ psg) {
  __shared__ __align__(16) half_t As[3 * 4096];
  __shared__ __align__(16) half_t Bs[3 * 16384];
  __shared__ float rmL[4][128];
  __shared__ float cmL[2][512];
  __shared__ float rsL[4][128];
  __shared__ float csL[2][512];

  const int nby = gridDim.y;  // 16
  long lid;
  xcd_swz(blockIdx.y + (long)nby * blockIdx.z, (long)nby * gridDim.z, lid);
  const int by = (int)(lid % nby);
  const int bz = (int)(lid / nby);

  const int t0 = threadIdx.x;
  const int lane = t0 & 63;
  const int wid = t0 >> 6;
  const int wm = wid >> 2, wn = wid & 3;
  const int m0 = by * 128;

  const half_t* Abase = Ap + ((long)bz * LP + m0) * HH;
  const half_t* Bbase = Bp + (long)bz * LQ * HH;

  const int c5 = lane & 31, hi = lane >> 5;
  const int sx = (c5 >> 1) & 3;
  const int ofs0 = c5 * 32 + ((hi ^ sx) << 3);
  const int ofs1 = c5 * 32 + (((2 | hi) ^ sx) << 3);

  f32x16 acc[2][4] = {};
  const int NT = HH / 32;   // 32

#pragma unroll
  for (int tt = 0; tt < 2; ++tt) {
    stage_op<128>(Abase + tt * 32, HH, As + tt * 4096, wid, lane);
    stage_op<512>(Bbase + tt * 32, HH, Bs + tt * 16384, wid, lane);
  }

  for (int t = 0; t < NT; ++t) {
    if (t + 1 < NT) asm volatile("s_waitcnt vmcnt(5)" ::: "memory");
    else            asm volatile("s_waitcnt vmcnt(0)" ::: "memory");
    __builtin_amdgcn_s_barrier();
    asm volatile("" ::: "memory");

    const half_t* Au = As + (t % 3) * 4096;
    const half_t* Bu = Bs + (t % 3) * 16384;
    f16x8 af[2][2], bf[4][2];
#pragma unroll
    for (int mf = 0; mf < 2; ++mf) {
      const half_t* p = Au + (wm * 64 + mf * 32) * 32;
      af[mf][0] = *(const f16x8*)(p + ofs0);
      af[mf][1] = *(const f16x8*)(p + ofs1);
    }
#pragma unroll
    for (int nf = 0; nf < 4; ++nf) {
      const half_t* p = Bu + (wn * 128 + nf * 32) * 32;
      bf[nf][0] = *(const f16x8*)(p + ofs0);
      bf[nf][1] = *(const f16x8*)(p + ofs1);
    }
    if (t + 2 < NT) {
      const int u2 = (t + 2) % 3;
      stage_op<128>(Abase + (t + 2) * 32, HH, As + u2 * 4096, wid, lane);
      stage_op<512>(Bbase + (t + 2) * 32, HH, Bs + u2 * 16384, wid, lane);
    }
    __builtin_amdgcn_s_setprio(1);
#pragma unroll
    for (int mf = 0; mf < 2; ++mf)
#pragma unroll
      for (int nf = 0; nf < 4; ++nf) {
        acc[mf][nf] = __builtin_amdgcn_mfma_f32_32x32x16_f16(af[mf][0], bf[nf][0], acc[mf][nf], 0, 0, 0);
        acc[mf][nf] = __builtin_amdgcn_mfma_f32_32x32x16_f16(af[mf][1], bf[nf][1], acc[mf][nf], 0, 0, 0);
      }
    __builtin_amdgcn_s_setprio(0);
  }

  // ===== pass1: row max / col max; pmg write =====
  float rmv[2][16], cmv[4];
#pragma unroll
  for (int m = 0; m < 2; ++m)
#pragma unroll
    for (int r = 0; r < 16; ++r) {
      float v = fmaxf(fmaxf(acc[m][0][r], acc[m][1][r]), fmaxf(acc[m][2][r], acc[m][3][r]));
#pragma unroll
      for (int o = 1; o < 32; o <<= 1) v = fmaxf(v, __shfl_xor(v, o, 64));
      rmv[m][r] = v;
    }
#pragma unroll
  for (int n = 0; n < 4; ++n) {
    float v = acc[0][n][0];
#pragma unroll
    for (int m = 0; m < 2; ++m)
#pragma unroll
      for (int r = 0; r < 16; ++r) v = fmaxf(v, acc[m][n][r]);
    v = fmaxf(v, __shfl_xor(v, 32, 64));
    cmv[n] = v;
  }
  if (c5 < 16) {
#pragma unroll
    for (int m = 0; m < 2; ++m)
      rmL[wn][wm * 64 + m * 32 + (c5 & 3) + 8 * (c5 >> 2) + 4 * hi] = rmv[m][c5];
  }
  if (hi == 0) {
#pragma unroll
    for (int n = 0; n < 4; ++n) cmL[wm][wn * 128 + n * 32 + c5] = cmv[n];
  }
  __syncthreads();
  if (t0 < 128)
    rmL[0][t0] = fmaxf(fmaxf(rmL[0][t0], rmL[1][t0]), fmaxf(rmL[2][t0], rmL[3][t0]));
  {
    float cm2 = fmaxf(cmL[0][t0 & 511], cmL[1][t0 & 511]);
    cmL[0][t0 & 511] = cm2;
    pmg[((long)bz * 16 + by) * LQ + (t0 & 511)] = cm2;
  }
  __syncthreads();
#pragma unroll
  for (int m = 0; m < 2; ++m)
#pragma unroll
    for (int r = 0; r < 16; ++r)
      rmv[m][r] = rmL[0][wm * 64 + m * 32 + (r & 3) + 8 * (r >> 2) + 4 * hi];
#pragma unroll
  for (int n = 0; n < 4; ++n) cmv[n] = cmL[0][wn * 128 + n * 32 + c5];

  // ===== pass2 (merged): one exp pass -> E store + col sums + row sums; acc <- p =====
  half_t* EB = EO + (long)bz * LP * LQ;
  float csW[4] = {0.f, 0.f, 0.f, 0.f};
  float rowS[2][16];
#pragma unroll
  for (int m = 0; m < 2; ++m)
#pragma unroll
    for (int r = 0; r < 16; ++r) {
      long grow = (long)(m0 + wm * 64 + m * 32 + (r & 3) + 8 * (r >> 2) + 4 * hi) * LQ;
      float s = 0.f;
#pragma unroll
      for (int n = 0; n < 4; ++n) {
        float a = acc[m][n][r];
        float e = __expf(a - cmv[n]);
        float p = __expf(a - rmv[m][r]);
        csW[n] += e;
        EB[grow + wn * 128 + n * 32 + c5] = (half_t)e;
        acc[m][n][r] = p;
        s += p;
      }
#pragma unroll
      for (int o = 1; o < 32; o <<= 1) s += __shfl_xor(s, o, 64);
      rowS[m][r] = s;
    }
#pragma unroll
  for (int n = 0; n < 4; ++n) csW[n] += __shfl_xor(csW[n], 32, 64);
  if (c5 < 16) {
#pragma unroll
    for (int m = 0; m < 2; ++m)
      rsL[wn][wm * 64 + m * 32 + (c5 & 3) + 8 * (c5 >> 2) + 4 * hi] = rowS[m][c5];
  }
  if (hi == 0) {
#pragma unroll
    for (int n = 0; n < 4; ++n) csL[wm][wn * 128 + n * 32 + c5] = csW[n];
  }
  __syncthreads();
  if (t0 < 128)
    rsL[0][t0] = 1.f / (rsL[0][t0] + rsL[1][t0] + rsL[2][t0] + rsL[3][t0]);
  psg[((long)bz * 16 + by) * LQ + (t0 & 511)] = csL[0][t0 & 511] + csL[1][t0 & 511];
  __syncthreads();

  // ===== pass3: Pp = p * rinv =====
  half_t* PpB = PpO + (long)bz * LP * LQ;
#pragma unroll
  for (int m = 0; m < 2; ++m)
#pragma unroll
    for (int r = 0; r < 16; ++r) {
      int row = wm * 64 + m * 32 + (r & 3) + 8 * (r >> 2) + 4 * hi;
      long grow = (long)(m0 + row) * LQ;
      float ri = rsL[0][row];
#pragma unroll
      for (int n = 0; n < 4; ++n)
        PpB[grow + wn * 128 + n * 32 + c5] = (half_t)(acc[m][n][r] * ri);
    }
}

// ================= 8-phase 256x256 GEMM core (lead-6, graded tail) =================
__device__ __forceinline__ void stage_half(const half_t* src, int ld, int k0,
                                           half_t* slot, int half_id, int wid, int lane) {
#pragma unroll
  for (int j = 0; j < 2; ++j) {
    int c = j * 512 + wid * 64 + lane;
    int lr = c >> 3, sl = c & 7;
    int gr = (lr & 63) + half_id * 64 + (lr >> 6) * 128;
    const half_t* g = src + (long)gr * ld + k0 + (((sl ^ (lr & 7))) << 3);
    __builtin_amdgcn_global_load_lds((cg_void*)g,
        (lds_void*)(slot + j * 4096 + wid * 512), 16, 0, 0);
  }
}

__device__ __forceinline__ void stage_s(int s, const half_t* Ab, const half_t* Bb,
                                        int lda, int ldb, half_t* lds, int NT,
                                        int wid, int lane) {
  int ts = s >> 2;
  if (ts >= NT) return;
  int kind = s & 3;
  half_t* slot = lds + (s & 7) * 8192;
  int k0 = ts * 64;
  if (kind == 0)      stage_half(Ab, lda, k0, slot, 0, wid, lane);
  else if (kind == 1) stage_half(Bb, ldb, k0, slot, 0, wid, lane);
  else if (kind == 2) stage_half(Bb, ldb, k0, slot, 1, wid, lane);
  else                stage_half(Ab, lda, k0, slot, 1, wid, lane);
}

template<int MODE>
__device__ __forceinline__ void core8p(const half_t* __restrict__ Ab,
                                       const half_t* __restrict__ Bb,
                                       void* __restrict__ cB,
                                       const float* __restrict__ biasB,
                                       int lda, int ldb, int ldc, int K,
                                       half_t* lds) {
  const int t0 = threadIdx.x;
  const int lane = t0 & 63;
  const int wid = t0 >> 6;
  const int wm = wid >> 2, wn = wid & 3;   // 2 x 4 waves
  const int fr = lane & 15, fs = lane >> 4;

  f32x4 acc[8][4] = {};
  const int NT = K >> 6;                   // K-tiles of 64

  // prologue: stages s=0..5 (lead 6); vmcnt(6) -> s<=2 resident
#pragma unroll
  for (int s = 0; s < 6; ++s) stage_s(s, Ab, Bb, lda, ldb, lds, NT, wid, lane);
  asm volatile("s_waitcnt vmcnt(6)" ::: "memory");
  __builtin_amdgcn_s_barrier();
  asm volatile("" ::: "memory");

  for (int t = 0; t < NT; ++t) {
    const int base4 = 4 * t;
    const half_t* slotA0 = lds + ((base4) & 7) * 8192;
    const half_t* slotB0 = lds + ((base4 + 1) & 7) * 8192;
    const half_t* slotB1 = lds + ((base4 + 2) & 7) * 8192;
    const half_t* slotA1 = lds + ((base4 + 3) & 7) * 8192;
    f16x8 bf[4][2];
#pragma unroll
    for (int p = 0; p < 4; ++p) {
      // ---- ds reads for this phase (guaranteed by previous phase's wait) ----
      f16x8 af[2][2];
      const half_t* aslot = (p < 2) ? slotA0 : slotA1;
      const int lrbase = wm * 64 + (p & 1) * 32;
#pragma unroll
      for (int i = 0; i < 2; ++i) {
        int lr = lrbase + i * 16 + fr;
#pragma unroll
        for (int kh = 0; kh < 2; ++kh)
          af[i][kh] = *(const f16x8*)&aslot[lr * 64 + (((fs + 4 * kh) ^ (lr & 7)) << 3)];
      }
      if (p == 0) {
        const half_t* bslot = (wn & 1) ? slotB1 : slotB0;
#pragma unroll
        for (int nf = 0; nf < 4; ++nf) {
          int lr = (wn >> 1) * 64 + nf * 16 + fr;
#pragma unroll
          for (int kh = 0; kh < 2; ++kh)
            bf[nf][kh] = *(const f16x8*)&bslot[lr * 64 + (((fs + 4 * kh) ^ (lr & 7)) << 3)];
        }
      }
      // ---- stage one half-tile (stream, lead 6) ----
      stage_s(base4 + p + 6, Ab, Bb, lda, ldb, lds, NT, wid, lane);
      // ---- graded counted wait ----
      if (t + 2 < NT) {
        asm volatile("s_waitcnt vmcnt(6)" ::: "memory");
      } else if (t + 2 == NT) {
        if (p < 2)       asm volatile("s_waitcnt vmcnt(6)" ::: "memory");
        else if (p == 2) asm volatile("s_waitcnt vmcnt(4)" ::: "memory");
        else             asm volatile("s_waitcnt vmcnt(2)" ::: "memory");
      } else {
        asm volatile("s_waitcnt vmcnt(0)" ::: "memory");
      }
      __builtin_amdgcn_s_barrier();
      asm volatile("s_waitcnt lgkmcnt(0)" ::: "memory");
      __builtin_amdgcn_sched_barrier(0);
      __builtin_amdgcn_s_setprio(1);
#pragma unroll
      for (int kh = 0; kh < 2; ++kh)
#pragma unroll
        for (int i = 0; i < 2; ++i)
#pragma unroll
          for (int nf = 0; nf < 4; ++nf)
            acc[p * 2 + i][nf] =
                __builtin_amdgcn_mfma_f32_16x16x32_f16(af[i][kh], bf[nf][kh], acc[p * 2 + i][nf], 0, 0, 0);
      __builtin_amdgcn_s_setprio(0);
      __builtin_amdgcn_s_barrier();
      asm volatile("" ::: "memory");
    }
  }

  // ---- epilogue: D row=(lane>>4)*4+j, col=lane&15 ----
  const int r0 = fs * 4;
#pragma unroll
  for (int nf = 0; nf < 4; ++nf) {
    int col = wn * 64 + nf * 16 + fr;
    float bv = 0.f;
    if constexpr (MODE == M_QPROJ) bv = biasB[col];
#pragma unroll
    for (int mf = 0; mf < 8; ++mf) {
      int row = wm * 128 + (mf >> 2) * 64 + ((mf >> 1) & 1) * 32 + (mf & 1) * 16 + r0;
#pragma unroll
      for (int j = 0; j < 4; j++) {
        if constexpr (MODE == M_QPROJ)
          ((half_t*)cB)[(long)(row + j) * ldc + col] = (half_t)(acc[mf][nf][j] + bv);
        else
          ((float*)cB)[(long)(row + j) * ldc + col] = acc[mf][nf][j];
      }
    }
  }
}

// qproj: grid (4, 64) = 256 blocks
__global__ __launch_bounds__(512, 1) void gemmq_k(const half_t* __restrict__ q16,
                                                  const half_t* __restrict__ w16,
                                                  half_t* __restrict__ qpj,
                                                  const float* __restrict__ Gb) {
  __shared__ __align__(16) half_t lds[8 * 8192];
  long lid;
  xcd_swz(blockIdx.x + 4L * blockIdx.y, 4L * gridDim.y, lid);
  const int bx = (int)(lid % 4);
  const int by = (int)(lid / 4);
  core8p<M_QPROJ>(q16 + (long)(by * 256) * HH,
                  w16 + (long)(bx * 256) * HH,
                  qpj + (long)(by * 256) * HH + bx * 256,
                  Gb + bx * 256, HH, HH, HH, HH, lds);
}

// fused m_p + m_q: grid (4, 10, 32); by<2 -> m_q tile (long K, starts early), else m_p
__global__ __launch_bounds__(512, 1) void gemm2_k(
    const half_t* __restrict__ Pp, const half_t* __restrict__ qT16, float* __restrict__ m_p,
    const half_t* __restrict__ Pq, const half_t* __restrict__ pT16, float* __restrict__ m_q) {
  __shared__ __align__(16) half_t lds[8 * 8192];
  long lid;
  xcd_swz(blockIdx.x + 4L * (blockIdx.y + 10L * blockIdx.z), 4L * 10 * 32, lid);
  const int bx = (int)(lid % 4);
  const long tmp = lid / 4;
  const int by = (int)(tmp % 10);
  const int bz = (int)(tmp / 10);

  if (by < 2) {
    core8p<M_OUT32>(Pq + (long)bz * LQ * LP + (long)(by * 256) * LP,
                    pT16 + (long)bz * HH * LP + (long)(bx * 256) * LP,
                    m_q + (long)bz * LQ * HH + (long)(by * 256) * HH + bx * 256,
                    nullptr, LP, LP, HH, LP, lds);
  } else {
    const int py = by - 2;
    core8p<M_OUT32>(Pp + (long)bz * LP * LQ + (long)(py * 256) * LQ,
                    qT16 + (long)bz * HH * LQ + (long)(bx * 256) * LQ,
                    m_p + (long)bz * LP * HH + (long)(py * 256) * HH + bx * 256,
                    nullptr, LQ, LQ, HH, LQ, lds);
  }
}

extern "C" void kernel_launch(void* const* d_in, const int* in_sizes, int n_in,
                              void* d_out, int out_size, void* d_ws, size_t ws_size,
                              hipStream_t stream) {
  const float* p_enc = (const float*)d_in[0];  // [B, LP, H]
  const float* q_enc = (const float*)d_in[1];  // [B, LQ, H]
  const float* Gw    = (const float*)d_in[2];  // [H, H]
  const float* Gb    = (const float*)d_in[3];  // [H]
  float* m_p = (float*)d_out;
  float* m_q = m_p + (long)BB * LP * HH;

  // workspace carve (~548 MB, ws is ~1.25 GiB)
  half_t* w16   = (half_t*)d_ws;                    // HH*HH
  half_t* q16   = w16 + (long)HH * HH;              // BB*LQ*HH
  half_t* qT16  = q16 + (long)BB * LQ * HH;         // BB*HH*LQ
  half_t* qpj16 = qT16 + (long)BB * HH * LQ;        // BB*LQ*HH
  half_t* p16   = qpj16 + (long)BB * LQ * HH;       // BB*LP*HH
  half_t* pT16  = p16 + (long)BB * LP * HH;         // BB*HH*LP
  half_t* Pp    = pT16 + (long)BB * HH * LP;        // BB*LP*LQ
  half_t* Ebuf  = Pp + (long)BB * LP * LQ;          // BB*LP*LQ
  half_t* Pq    = Ebuf + (long)BB * LP * LQ;        // BB*LQ*LP
  float*  cmaxb = (float*)(Pq + (long)BB * LQ * LP);
  float*  cinvb = cmaxb + (long)BB * LQ;
  float*  pmg   = cinvb + (long)BB * LQ;            // BB*16*LQ
  float*  psg   = pmg + (long)BB * 16 * LQ;         // BB*16*LQ

  cvt16_k<<<HH * HH / 1024, 256, 0, stream>>>(Gw, w16);

  // fused q+p cvt/transpose
  cvt2_k<<<dim3(HH / 64, 40, BB), 256, 0, stream>>>(q_enc, q16, qT16, p_enc, p16, pT16);

  // qproj16 = q16 . w16^T + Gb   (M=16384, N=HH, K=HH) — 8-phase core
  gemmq_k<<<dim3(4, 64, 1), 512, 0, stream>>>(q16, w16, qpj16, Gb);

  // fused att GEMM: Pp, E, col partials
  attf_k<<<dim3(1, LP / 128, BB), 512, 0, stream>>>(p16, qpj16, Pp, Ebuf, pmg, psg);

  // finalize col stats; build Pq from E
  cfin_k<<<BB * LQ / 256, 256, 0, stream>>>(pmg, psg, cmaxb, cinvb);
  pq_k<<<dim3(LQ / 64, LP / 64, BB), 256, 0, stream>>>(Ebuf, Pq, pmg, cmaxb, cinvb);

  // fused m_p + m_q (8-phase core, lead-6 / graded-tail counted vmcnt)
  gemm2_k<<<dim3(4, 10, BB), 512, 0, stream>>>(Pp, qT16, m_p, Pq, pT16, m_q);
}